// Round 7
// baseline (494.235 us; speedup 1.0000x reference)
//
#include <hip/hip_runtime.h>

#define NUM_LAYERS 10
#define HIDDEN 5
#define SEQ 457
#define BATCH 4096
#define OUT_DIM 457
#define KD 2285
#define NKT 72
#define OPAD 512

typedef __attribute__((ext_vector_type(8))) short short8;
typedef __attribute__((ext_vector_type(4))) float f32x4;
typedef unsigned long long ull;
typedef unsigned short ushort;

__device__ __forceinline__ float frcp(float x){ return __builtin_amdgcn_rcpf(x); }
__device__ __forceinline__ float fexp2(float x){ return __builtin_amdgcn_exp2f(x); }
__device__ __forceinline__ ushort f2bf(float f){
    unsigned u = __float_as_uint(f);
    u = (u + 0x7FFFu + ((u>>16)&1u)) >> 16;
    return (ushort)u;
}
__device__ __forceinline__ float bf2f(ushort h){ return __uint_as_float(((unsigned)h) << 16); }
__device__ __forceinline__ unsigned cvtpk(float a, float b){
    unsigned r;
    asm("v_cvt_pk_bf16_f32 %0, %1, %2" : "=v"(r) : "v"(a), "v"(b));
    return r;
}
__device__ __forceinline__ float lo16f(unsigned p){ return __uint_as_float(p << 16); }
__device__ __forceinline__ float hi16f(unsigned p){ return __uint_as_float(p & 0xFFFF0000u); }
__device__ __forceinline__ void act4(const f32x4 d, float& i_, float& f_, float& g_, float& o_){
    i_ = frcp(1.f + fexp2(d[0]));
    f_ = frcp(1.f + fexp2(d[1]));
    g_ = 1.f - 2.f*frcp(1.f + fexp2(d[2]));
    o_ = frcp(1.f + fexp2(d[3]));
}
__device__ __forceinline__ float tanhc(float c){ return 1.f - 2.f*frcp(1.f + fexp2(2.8853900817779268f*c)); }

// ---------------------------------------------------------------------------
// Skew-4 MFMA LSTM. 16 batches/block, 11 waves (10 layer + 1 ghost feeder).
// Layer l at interval s computes t = 4(s-l)..4(s-l)+3; ONE barrier/interval
// (124 total). Own-h between in-interval timesteps flows via same-wave LDS
// write->read (DS in-order per wave). Slot per (l,b) = 92 shorts (184 B,
// bank-spread: m*46 mod 32 covers 16 distinct banks); 4 sub-slots of 20
// shorts: [in_hi5 h_hi5 in_lo5 h_lo5]. K=32 MFMA packing: k0-9 a_hi*w_hi,
// k10-19 a_lo*w_hi, k20-29 a_hi*w_lo, k30-31 zero-W.
// ---------------------------------------------------------------------------
#define GB 16
#define NW 11
#define SUB_SH 20
#define SLOT_SH 92
#define LBUF_SH (NUM_LAYERS*GB*SLOT_SH)    // 14720 shorts
#define LBUF_B  (LBUF_SH*2)                // 29440 bytes
#define NINT 124                           // ceil(457/4)+9

__global__ __launch_bounds__(64*NW) void lstm_kernel(
    const float* __restrict__ x,      // [B][SEQ][5]
    const float* __restrict__ W_ih,   // [10][20][5]
    const float* __restrict__ W_hh,
    const float* __restrict__ b_ih,
    const float* __restrict__ b_hh,
    ushort* __restrict__ HbP)         // packed [256 bg][72 kk][64 L][8]
{
    __shared__ ull CsQ[2*LBUF_SH/4];  // 58,880 B
    ushort* Cs = (ushort*)CsQ;
    const int tid = threadIdx.x;
    const int lane = tid & 63;
    const int lS = __builtin_amdgcn_readfirstlane(tid >> 6);
    const int bg = blockIdx.x;
    const size_t hbBase = (size_t)bg * (NKT*512);

    for (int i = tid; i < 2*LBUF_SH/4; i += 64*NW) CsQ[i] = 0;
    __syncthreads();

    const int m  = lane & 15;
    const int kg = lane >> 4;

    short8 wf0{}, wf1{};
    f32x4 bias0{}, bias1{};
    float c0 = 0.f, c4 = 0.f;
    float xr0=0,xr1=0,xr2=0,xr3=0,xr4=0;
    const float* xb2 = nullptr;
    const int tt4 = lane >> 4;        // ghost: time sub-slot 0..3
    const char* rdB = nullptr;
    int off0 = 0, off1 = 0;
    int slotSh = 0;
    char* gw0 = nullptr;

    if (lS < NUM_LAYERS) {
        const int l = lS;
        { // wf0: rows = gatecol m (j=m>>2, g=m&3)
            const int j = m >> 2, g = m & 3;
            const float scg = (g == 2) ? 2.8853900817779268f : -1.4426950408889634f;
            const int row = l*20 + g*5 + j;
#pragma unroll
            for (int e = 0; e < 8; ++e) {
                const int k = kg*8 + e;
                ushort v = 0;
                if (k < 30) {
                    const int ki = (k < 10) ? k : (k < 20) ? k-10 : k-20;
                    const float w = scg * ((ki < 5) ? W_ih[row*5+ki] : W_hh[row*5+ki-5]);
                    const ushort hi = f2bf(w);
                    v = (k >= 20) ? f2bf(w - bf2f(hi)) : hi;
                }
                wf0[e] = (short)v;
            }
        }
        { // wf1: rows 0-3 = j=4 gates, rest zero
#pragma unroll
            for (int e = 0; e < 8; ++e) {
                ushort v = 0;
                if (m < 4) {
                    const int g = m;
                    const float scg = (g == 2) ? 2.8853900817779268f : -1.4426950408889634f;
                    const int row = l*20 + g*5 + 4;
                    const int k = kg*8 + e;
                    if (k < 30) {
                        const int ki = (k < 10) ? k : (k < 20) ? k-10 : k-20;
                        const float w = scg * ((ki < 5) ? W_ih[row*5+ki] : W_hh[row*5+ki-5]);
                        const ushort hi = f2bf(w);
                        v = (k >= 20) ? f2bf(w - bf2f(hi)) : hi;
                    }
                }
                wf1[e] = (short)v;
            }
        }
#pragma unroll
        for (int r = 0; r < 4; ++r) {
            const float scg = (r == 2) ? 2.8853900817779268f : -1.4426950408889634f;
            bias0[r] = scg * (b_ih[l*20 + r*5 + kg] + b_hh[l*20 + r*5 + kg]);
            bias1[r] = (kg == 0) ? scg * (b_ih[l*20 + r*5 + 4] + b_hh[l*20 + r*5 + 4]) : 0.f;
        }
        off0 = (kg==0) ? 0 : (kg==1) ? 16 : (kg==2) ? 32 : 8;
        off1 = (kg==0) ? 8 : (kg==1) ? 24 : (kg==2) ? 0 : 16;
        slotSh = (l*16 + m) * SLOT_SH;
        rdB = (const char*)Cs + slotSh*2;
    } else {
        // ghost wave: lane = (tt4, b)
        xb2 = x + (size_t)(bg*GB + m) * (SEQ*HIDDEN);
        gw0 = (char*)Cs + (m*SLOT_SH + tt4*SUB_SH)*2;   // layer-0 slot, buf 0 base
        // zero kk=71 pad slab of this bg
        ull* slab = (ull*)(HbP + hbBase + 71*512);
        slab[lane] = 0; slab[lane + 64] = 0;
    }
    __syncthreads();

    if (lS == NUM_LAYERS) {
        // seed buf0 with x(t=tt4); prefetch x(4+tt4)
        const float v0=xb2[tt4*5+0], v1=xb2[tt4*5+1], v2=xb2[tt4*5+2],
                    v3=xb2[tt4*5+3], v4=xb2[tt4*5+4];
        const unsigned p01=cvtpk(v0,v1), p23=cvtpk(v2,v3);
        const unsigned q01=cvtpk(v0-lo16f(p01), v1-hi16f(p01)),
                       q23=cvtpk(v2-lo16f(p23), v3-hi16f(p23));
        const ushort p4=f2bf(v4);
        *(unsigned*)(gw0+0)=p01;  *(unsigned*)(gw0+4)=p23;  *(ushort*)(gw0+8)=p4;
        *(unsigned*)(gw0+20)=q01; *(unsigned*)(gw0+24)=q23; *(ushort*)(gw0+28)=f2bf(v4-bf2f(p4));
        xr0=xb2[(4+tt4)*5+0]; xr1=xb2[(4+tt4)*5+1]; xr2=xb2[(4+tt4)*5+2];
        xr3=xb2[(4+tt4)*5+3]; xr4=xb2[(4+tt4)*5+4];
    }
    __syncthreads();

    int cur = 0;
    for (int s = 0; s < NINT; ++s) {
        if (lS < NUM_LAYERS) {
            const int t0 = 4*(s - lS);
            const char* rbase = rdB + cur*LBUF_B;
            ushort* curS = Cs + cur*LBUF_SH + slotSh;
            ushort* nxtS = Cs + (cur^1)*LBUF_SH + slotSh;
            ushort* nxtN = nxtS + 16*SLOT_SH;     // slot (l+1, m)
#pragma unroll
            for (int tt = 0; tt < 4; ++tt) {
                union { short8 v; ull q[2]; } bf;
                bf.q[0] = *(const ull*)(rbase + tt*40 + off0);
                bf.q[1] = *(const ull*)(rbase + tt*40 + off1);
                f32x4 d0 = __builtin_amdgcn_mfma_f32_16x16x32_bf16(wf0, bf.v, bias0, 0,0,0);
                f32x4 d4 = __builtin_amdgcn_mfma_f32_16x16x32_bf16(wf1, bf.v, bias1, 0,0,0);
                float ig,fg,gg,og, i4,f4,g4,o4;
                act4(d0, ig,fg,gg,og);
                act4(d4, i4,f4,g4,o4);
                const int t = t0 + tt;
                if (t >= 0 && t < SEQ) {
                    c0 = fg*c0 + ig*gg;
                    const float h0 = og * tanhc(c0);
                    c4 = f4*c4 + i4*g4;
                    const float h4 = o4 * tanhc(c4);
                    const unsigned ph = cvtpk(h0, h4);
                    const unsigned pl = cvtpk(h0 - lo16f(ph), h4 - hi16f(ph));
                    ushort* ownH = (tt < 3) ? (curS + (tt+1)*SUB_SH) : nxtS;
                    ownH[5+kg]  = (ushort)ph;
                    ownH[15+kg] = (ushort)pl;
                    if (kg == 0) { ownH[9] = (ushort)(ph>>16); ownH[19] = (ushort)(pl>>16); }
                    if (lS < NUM_LAYERS-1) {
                        ushort* nin = nxtN + tt*SUB_SH;
                        nin[kg]    = (ushort)ph;
                        nin[10+kg] = (ushort)pl;
                        if (kg == 0) { nin[4] = (ushort)(ph>>16); nin[14] = (ushort)(pl>>16); }
                    } else {
                        const int k = t*5 + kg;
                        HbP[hbBase + (k>>5)*512 + ((k>>3)&3)*128 + m*8 + (k&7)] = (ushort)ph;
                        if (kg == 0) {
                            const int k4 = t*5 + 4;
                            HbP[hbBase + (k4>>5)*512 + ((k4>>3)&3)*128 + m*8 + (k4&7)] = (ushort)(ph>>16);
                        }
                    }
                }
            }
        } else {
            // ghost: write x(4(s+1)+tt4) into nxt buf; prefetch x(4(s+2)+tt4)
            const int tw = 4*(s+1) + tt4;
            char* gw = gw0 + (cur^1)*LBUF_B;
            if (tw < SEQ) {
                const unsigned p01=cvtpk(xr0,xr1), p23=cvtpk(xr2,xr3);
                const unsigned q01=cvtpk(xr0-lo16f(p01), xr1-hi16f(p01)),
                               q23=cvtpk(xr2-lo16f(p23), xr3-hi16f(p23));
                const ushort p4=f2bf(xr4);
                *(unsigned*)(gw+0)=p01;  *(unsigned*)(gw+4)=p23;  *(ushort*)(gw+8)=p4;
                *(unsigned*)(gw+20)=q01; *(unsigned*)(gw+24)=q23; *(ushort*)(gw+28)=f2bf(xr4-bf2f(p4));
            }
            int tn = 4*(s+2) + tt4; if (tn > SEQ-1) tn = SEQ-1;
            xr0=xb2[tn*5+0]; xr1=xb2[tn*5+1]; xr2=xb2[tn*5+2];
            xr3=xb2[tn*5+3]; xr4=xb2[tn*5+4];
        }
        __syncthreads();
        cur ^= 1;
    }
}

// ---------------------------------------------------------------------------
// fcW -> packed bf16 hi/lo fragments: [og(32)][kk(72)][L(64)][e(8)]
// ---------------------------------------------------------------------------
__global__ __launch_bounds__(256) void convw_kernel(
    const float* __restrict__ fcW,
    ushort* __restrict__ WhiP,
    ushort* __restrict__ WloP)
{
    const int tidg = blockIdx.x * 256 + threadIdx.x;
    if (tidg >= 32*NKT*64) return;
    const int L  = tidg & 63;
    const int kk = (tidg >> 6) % NKT;
    const int og = tidg / (64*NKT);
    const int o = og*16 + (L & 15);
    const int kb = kk*32 + ((L >> 4) << 3);
    short8 hi8{}, lo8{};
#pragma unroll
    for (int e = 0; e < 8; ++e) {
        const int k = kb + e;
        float v = 0.f;
        if (o < OUT_DIM && k < KD) v = fcW[(size_t)o*KD + k];
        const ushort hi = f2bf(v);
        hi8[e] = (short)hi;
        lo8[e] = (short)f2bf(v - bf2f(hi));
    }
    *(short8*)&WhiP[(size_t)tidg*8] = hi8;
    *(short8*)&WloP[(size_t)tidg*8] = lo8;
}

// ---------------------------------------------------------------------------
// FC: packed-fragment MFMA GEMM; 8 waves/block share one ogB (W locality).
// ---------------------------------------------------------------------------
__global__ __launch_bounds__(512) void fc_kernel(
    const ushort* __restrict__ HbP,    // [256][72][64][8]
    const ushort* __restrict__ WhiP,   // [32][72][64][8]
    const ushort* __restrict__ WloP,
    const float* __restrict__ fcb,
    float* __restrict__ out)           // [BATCH][OUT_DIM]
{
    const int lane = threadIdx.x & 63;
    const int w = threadIdx.x >> 6;
    const int bgi = blockIdx.x*8 + w;          // 0..255
    const int ogB = blockIdx.y*4;              // 0..28
    const ushort* Ap  = HbP  + (size_t)bgi*(NKT*512) + lane*8;
    const ushort* Wh0 = WhiP + (size_t)(ogB+0)*(NKT*512) + lane*8;
    const ushort* Wh1 = WhiP + (size_t)(ogB+1)*(NKT*512) + lane*8;
    const ushort* Wh2 = WhiP + (size_t)(ogB+2)*(NKT*512) + lane*8;
    const ushort* Wh3 = WhiP + (size_t)(ogB+3)*(NKT*512) + lane*8;
    const ushort* Wl0 = WloP + (size_t)(ogB+0)*(NKT*512) + lane*8;
    const ushort* Wl1 = WloP + (size_t)(ogB+1)*(NKT*512) + lane*8;
    const ushort* Wl2 = WloP + (size_t)(ogB+2)*(NKT*512) + lane*8;
    const ushort* Wl3 = WloP + (size_t)(ogB+3)*(NKT*512) + lane*8;

    f32x4 acc0{}, acc1{}, acc2{}, acc3{};

    short8 a_c   = *(const short8*)(Ap);
    short8 wh0_c = *(const short8*)(Wh0);
    short8 wh1_c = *(const short8*)(Wh1);
    short8 wh2_c = *(const short8*)(Wh2);
    short8 wh3_c = *(const short8*)(Wh3);
    short8 wl0_c = *(const short8*)(Wl0);
    short8 wl1_c = *(const short8*)(Wl1);
    short8 wl2_c = *(const short8*)(Wl2);
    short8 wl3_c = *(const short8*)(Wl3);

    for (int kk = 0; kk < NKT; ++kk) {
        const int kb = (kk+1 < NKT) ? (kk+1)*512 : kk*512;
        const short8 a_n   = *(const short8*)(Ap  + kb);
        const short8 wh0_n = *(const short8*)(Wh0 + kb);
        const short8 wh1_n = *(const short8*)(Wh1 + kb);
        const short8 wh2_n = *(const short8*)(Wh2 + kb);
        const short8 wh3_n = *(const short8*)(Wh3 + kb);
        const short8 wl0_n = *(const short8*)(Wl0 + kb);
        const short8 wl1_n = *(const short8*)(Wl1 + kb);
        const short8 wl2_n = *(const short8*)(Wl2 + kb);
        const short8 wl3_n = *(const short8*)(Wl3 + kb);

        acc0 = __builtin_amdgcn_mfma_f32_16x16x32_bf16(a_c, wh0_c, acc0, 0,0,0);
        acc1 = __builtin_amdgcn_mfma_f32_16x16x32_bf16(a_c, wh1_c, acc1, 0,0,0);
        acc2 = __builtin_amdgcn_mfma_f32_16x16x32_bf16(a_c, wh2_c, acc2, 0,0,0);
        acc3 = __builtin_amdgcn_mfma_f32_16x16x32_bf16(a_c, wh3_c, acc3, 0,0,0);
        acc0 = __builtin_amdgcn_mfma_f32_16x16x32_bf16(a_c, wl0_c, acc0, 0,0,0);
        acc1 = __builtin_amdgcn_mfma_f32_16x16x32_bf16(a_c, wl1_c, acc1, 0,0,0);
        acc2 = __builtin_amdgcn_mfma_f32_16x16x32_bf16(a_c, wl2_c, acc2, 0,0,0);
        acc3 = __builtin_amdgcn_mfma_f32_16x16x32_bf16(a_c, wl3_c, acc3, 0,0,0);

        a_c = a_n;
        wh0_c = wh0_n; wh1_c = wh1_n; wh2_c = wh2_n; wh3_c = wh3_n;
        wl0_c = wl0_n; wl1_c = wl1_n; wl2_c = wl2_n; wl3_c = wl3_n;
    }

    const int ocol = lane & 15;
    const int br0 = (lane >> 4) * 4;
    const int b0 = bgi * 16;
#pragma unroll
    for (int nb = 0; nb < 4; ++nb) {
        const int o = (ogB + nb)*16 + ocol;
        if (o < OUT_DIM) {
            const float bias = fcb[o];
            const f32x4 acc = (nb==0) ? acc0 : (nb==1) ? acc1 : (nb==2) ? acc2 : acc3;
#pragma unroll
            for (int r = 0; r < 4; ++r) {
                out[(size_t)(b0 + br0 + r)*OUT_DIM + o] = acc[r] + bias;
            }
        }
    }
}

extern "C" void kernel_launch(void* const* d_in, const int* in_sizes, int n_in,
                              void* d_out, int out_size, void* d_ws, size_t ws_size,
                              hipStream_t stream) {
    const float* x    = (const float*)d_in[0];
    const float* W_ih = (const float*)d_in[3];
    const float* W_hh = (const float*)d_in[4];
    const float* b_ih = (const float*)d_in[5];
    const float* b_hh = (const float*)d_in[6];
    const float* fcW  = (const float*)d_in[7];
    const float* fcb  = (const float*)d_in[8];
    float* out = (float*)d_out;

    ushort* HbP  = (ushort*)d_ws;
    ushort* WhiP = (ushort*)((char*)d_ws + (size_t)256*NKT*512*2);
    ushort* WloP = (ushort*)((char*)d_ws + (size_t)256*NKT*512*2 + (size_t)32*NKT*512*2);

    lstm_kernel<<<dim3(BATCH/GB), dim3(64*NW), 0, stream>>>(
        x, W_ih, W_hh, b_ih, b_hh, HbP);

    convw_kernel<<<dim3((32*NKT*64 + 255)/256), dim3(256), 0, stream>>>(fcW, WhiP, WloP);

    fc_kernel<<<dim3(32, 8), dim3(512), 0, stream>>>(HbP, WhiP, WloP, fcb, out);
}